// Round 10
// baseline (358.865 us; speedup 1.0000x reference)
//
#include <hip/hip_runtime.h>

#define IN_F 32
#define HID 64
#define N_LAYERS 3
#define BN_EPS 1e-5f

__device__ __forceinline__ unsigned short f2bf(float x) {
    unsigned u = __float_as_uint(x);
    u += 0x7fffu + ((u >> 16) & 1u);
    return (unsigned short)(u >> 16);
}
__device__ __forceinline__ float bflo(unsigned v) { return __uint_as_float(v << 16); }
__device__ __forceinline__ float bfhi(unsigned v) { return __uint_as_float(v & 0xffff0000u); }

// ---------------- CSR build ----------------
__global__ __launch_bounds__(256) void k_zero(int* cnt, int* cursor, float* statsAll, int n) {
    int i = blockIdx.x * blockDim.x + threadIdx.x;
    if (i < n) cnt[i] = 0;
    if (i == 0) *cursor = 0;
    if (i < 2 * HID * N_LAYERS) statsAll[i] = 0.0f;
}

__global__ __launch_bounds__(256) void k_hist_rank(const int* __restrict__ dst, int* cnt,
                                                   unsigned short* __restrict__ rank, int e) {
    int i = blockIdx.x * blockDim.x + threadIdx.x;
    if (i >= e) return;
    int r = atomicAdd(&cnt[dst[i]], 1);
    rank[i] = (unsigned short)r;
}

__global__ __launch_bounds__(256) void k_assign(const int* __restrict__ cnt, int* rowbeg,
                                                float* dinv, int* cursor, int n) {
    int i = blockIdx.x * blockDim.x + threadIdx.x;
    int lane = threadIdx.x & 63;
    int c = (i < n) ? cnt[i] : 0;
    int s = c;
#pragma unroll
    for (int off = 1; off < 64; off <<= 1) {
        int t = __shfl_up(s, off, 64);
        if (lane >= off) s += t;
    }
    int total = __shfl(s, 63, 64);
    int base = 0;
    if (lane == 63) base = atomicAdd(cursor, total);
    base = __shfl(base, 63, 64);
    if (i < n) {
        rowbeg[i] = base + s - c;
        dinv[i] = rsqrtf((float)(c + 1));
    }
}

__global__ __launch_bounds__(256) void k_fill(const int* __restrict__ src,
                                              const int* __restrict__ dst,
                                              const int* __restrict__ rowbeg,
                                              const unsigned short* __restrict__ rank,
                                              unsigned short* __restrict__ csr_src, int e) {
    int i = blockIdx.x * blockDim.x + threadIdx.x;
    if (i >= e) return;
    int pos = rowbeg[dst[i]] + (int)rank[i];
    csr_src[pos] = (unsigned short)src[i];
}

// ---------------- fused dense ops: 8-node outer-product per wave ----------------
// Per k-step: ONE per-lane W read (lane-consecutive, conflict-free) reused for 8 FMAs;
// multiplicands via wave-uniform ds_read_b128 broadcast (4 k per read).
__global__ __launch_bounds__(256) void k_embed_conv(const float* __restrict__ x,
                                                    const float* __restrict__ We,
                                                    const float* __restrict__ be,
                                                    const float* __restrict__ Wc,
                                                    const float* __restrict__ bc,
                                                    const float* __restrict__ dinv,
                                                    float* __restrict__ h,
                                                    unsigned short* __restrict__ t2b, int n) {
    __shared__ float sWe[IN_F * HID];    // 8 KB
    __shared__ float sWc[HID * HID];     // 16 KB
    __shared__ float shx[4][8][IN_F];    // 4 KB  (wave-private x rows)
    __shared__ float shh[4][8 * HID];    // 8 KB  (wave-private h rows)
    for (int i = threadIdx.x; i < IN_F * HID; i += blockDim.x) sWe[i] = We[i];
    for (int i = threadIdx.x; i < HID * HID; i += blockDim.x) sWc[i] = Wc[i];
    __syncthreads();

    int f = threadIdx.x & 63;
    int wv = threadIdx.x >> 6;
    int plane = f >> 5, fin = f & 31;
    float bef = be[f], bcf = bc[f];
    int ml = f >> 3, sub = f & 7;        // x-staging roles
    int wgid = blockIdx.x * 4 + wv;

    for (int iter = 0; iter < 2; ++iter) {
        int base = wgid * 16 + iter * 8;
        if (base >= n) break;

        // stage 8 x rows (coalesced float4; wave-private, no barrier)
        int xnode = base + ml;
        float4 xv = (xnode < n) ? ((const float4*)(x + (size_t)xnode * IN_F))[sub]
                                : make_float4(0.f, 0.f, 0.f, 0.f);
        ((float4*)&shx[wv][ml][0])[sub] = xv;

        // embed: h[m][f] = relu(sum_k x[m][k] * We[k][f] + be[f])
        float acc[8];
#pragma unroll
        for (int m = 0; m < 8; ++m) acc[m] = bef;
#pragma unroll
        for (int k4 = 0; k4 < IN_F / 4; ++k4) {
            float w0 = sWe[(k4 * 4 + 0) * HID + f];
            float w1 = sWe[(k4 * 4 + 1) * HID + f];
            float w2 = sWe[(k4 * 4 + 2) * HID + f];
            float w3 = sWe[(k4 * 4 + 3) * HID + f];
#pragma unroll
            for (int m = 0; m < 8; ++m) {
                float4 xq = ((const float4*)&shx[wv][m][0])[k4];   // uniform broadcast
                acc[m] = fmaf(xq.x, w0, acc[m]);
                acc[m] = fmaf(xq.y, w1, acc[m]);
                acc[m] = fmaf(xq.z, w2, acc[m]);
                acc[m] = fmaf(xq.w, w3, acc[m]);
            }
        }
#pragma unroll
        for (int m = 0; m < 8; ++m) {
            float hv = fmaxf(acc[m], 0.0f);
            int node = base + m;
            if (node < n) h[(size_t)node * HID + f] = hv;
            shh[wv][m * HID + f] = hv;
        }

        // conv: t[m][f] = (sum_k h[m][k] * Wc[k][f] + bc[f]) * dinv[m]
#pragma unroll
        for (int m = 0; m < 8; ++m) acc[m] = bcf;
#pragma unroll
        for (int k4 = 0; k4 < HID / 4; ++k4) {
            float w0 = sWc[(k4 * 4 + 0) * HID + f];
            float w1 = sWc[(k4 * 4 + 1) * HID + f];
            float w2 = sWc[(k4 * 4 + 2) * HID + f];
            float w3 = sWc[(k4 * 4 + 3) * HID + f];
#pragma unroll
            for (int m = 0; m < 8; ++m) {
                float4 hq = ((const float4*)&shh[wv][m * HID])[k4];   // uniform broadcast
                acc[m] = fmaf(hq.x, w0, acc[m]);
                acc[m] = fmaf(hq.y, w1, acc[m]);
                acc[m] = fmaf(hq.z, w2, acc[m]);
                acc[m] = fmaf(hq.w, w3, acc[m]);
            }
        }
#pragma unroll
        for (int m = 0; m < 8; ++m) {
            int node = base + m;
            if (node < n)
                t2b[(size_t)plane * n * 32 + (size_t)node * 32 + fin] = f2bf(acc[m] * dinv[node]);
        }
    }
}

__global__ __launch_bounds__(256) void k_bn_conv(const float* __restrict__ agg,
                                                 const float* __restrict__ stats,
                                                 const float* __restrict__ gamma,
                                                 const float* __restrict__ beta,
                                                 const float* __restrict__ W,
                                                 const float* __restrict__ b,
                                                 const float* __restrict__ dinv,
                                                 float* __restrict__ h,
                                                 unsigned short* __restrict__ t2b, int n, float invN) {
    __shared__ float sW[HID * HID];      // 16 KB
    __shared__ float shh[4][8 * HID];    // 8 KB
    for (int i = threadIdx.x; i < HID * HID; i += blockDim.x) sW[i] = W[i];
    __syncthreads();

    int f = threadIdx.x & 63;
    int wv = threadIdx.x >> 6;
    int plane = f >> 5, fin = f & 31;
    float mu = stats[f] * invN;
    float var = fmaxf(stats[HID + f] * invN - mu * mu, 0.0f);
    float scale = rsqrtf(var + BN_EPS) * gamma[f];
    float shift = beta[f];
    float bf = b[f];
    int wgid = blockIdx.x * 4 + wv;

    for (int iter = 0; iter < 2; ++iter) {
        int base = wgid * 16 + iter * 8;
        if (base >= n) break;

        float av[8], hold[8];
#pragma unroll
        for (int m = 0; m < 8; ++m) {
            int node = base + m;
            if (node < n) {
                size_t gid = (size_t)node * HID + f;
                av[m] = agg[gid]; hold[m] = h[gid];
            } else { av[m] = 0.f; hold[m] = 0.f; }
        }
        float acc[8];
#pragma unroll
        for (int m = 0; m < 8; ++m) {
            float bnv = (av[m] - mu) * scale + shift;
            float hv = fmaxf(bnv, 0.0f) + hold[m];
            int node = base + m;
            if (node < n) h[(size_t)node * HID + f] = hv;
            shh[wv][m * HID + f] = hv;
            acc[m] = bf;
        }
#pragma unroll
        for (int k4 = 0; k4 < HID / 4; ++k4) {
            float w0 = sW[(k4 * 4 + 0) * HID + f];
            float w1 = sW[(k4 * 4 + 1) * HID + f];
            float w2 = sW[(k4 * 4 + 2) * HID + f];
            float w3 = sW[(k4 * 4 + 3) * HID + f];
#pragma unroll
            for (int m = 0; m < 8; ++m) {
                float4 hq = ((const float4*)&shh[wv][m * HID])[k4];
                acc[m] = fmaf(hq.x, w0, acc[m]);
                acc[m] = fmaf(hq.y, w1, acc[m]);
                acc[m] = fmaf(hq.z, w2, acc[m]);
                acc[m] = fmaf(hq.w, w3, acc[m]);
            }
        }
#pragma unroll
        for (int m = 0; m < 8; ++m) {
            int node = base + m;
            if (node < n)
                t2b[(size_t)plane * n * 32 + (size_t)node * 32 + fin] = f2bf(acc[m] * dinv[node]);
        }
    }
}

// one 4-lane group per node per plane; 1-D grid, plane = blockIdx.x & 1 (XCD parity:
// each XCD's L2 holds ONE 3.2 MB plane table).
__global__ __launch_bounds__(256) void k_aggregate(const int* __restrict__ rowbeg,
                                                   const int* __restrict__ cnt,
                                                   const unsigned short* __restrict__ csr_src,
                                                   const unsigned short* __restrict__ t2b,
                                                   const float* __restrict__ dinv,
                                                   float* __restrict__ agg,
                                                   float* __restrict__ stats, int n) {
    __shared__ float lsum[HID], lsq[HID];
    if (threadIdx.x < HID) { lsum[threadIdx.x] = 0.0f; lsq[threadIdx.x] = 0.0f; }
    __syncthreads();

    const int plane = blockIdx.x & 1;
    const unsigned short* tb = t2b + (size_t)plane * n * 32;

    int l4 = threadIdx.x & 3;
    int node = (blockIdx.x >> 1) * 64 + (threadIdx.x >> 2);

    float4 r0 = make_float4(0.f, 0.f, 0.f, 0.f);
    float4 r1 = make_float4(0.f, 0.f, 0.f, 0.f);

    if (node < n) {
        int beg = rowbeg[node], end = beg + cnt[node];
        uint4 sv = ((const uint4*)(tb + (size_t)node * 32))[l4];
        float4 a0, a1;
        a0.x = bflo(sv.x); a0.y = bfhi(sv.x); a0.z = bflo(sv.y); a0.w = bfhi(sv.y);
        a1.x = bflo(sv.z); a1.y = bfhi(sv.z); a1.z = bflo(sv.w); a1.w = bfhi(sv.w);
        int j = beg;
        for (; j + 8 <= end; j += 8) {
            int s0 = csr_src[j + 0], s1 = csr_src[j + 1];
            int s2 = csr_src[j + 2], s3 = csr_src[j + 3];
            int s4 = csr_src[j + 4], s5 = csr_src[j + 5];
            int s6 = csr_src[j + 6], s7 = csr_src[j + 7];
            uint4 v0 = ((const uint4*)(tb + (size_t)s0 * 32))[l4];
            uint4 v1 = ((const uint4*)(tb + (size_t)s1 * 32))[l4];
            uint4 v2 = ((const uint4*)(tb + (size_t)s2 * 32))[l4];
            uint4 v3 = ((const uint4*)(tb + (size_t)s3 * 32))[l4];
            uint4 v4 = ((const uint4*)(tb + (size_t)s4 * 32))[l4];
            uint4 v5 = ((const uint4*)(tb + (size_t)s5 * 32))[l4];
            uint4 v6 = ((const uint4*)(tb + (size_t)s6 * 32))[l4];
            uint4 v7 = ((const uint4*)(tb + (size_t)s7 * 32))[l4];
            a0.x += bflo(v0.x) + bflo(v1.x) + bflo(v2.x) + bflo(v3.x)
                  + bflo(v4.x) + bflo(v5.x) + bflo(v6.x) + bflo(v7.x);
            a0.y += bfhi(v0.x) + bfhi(v1.x) + bfhi(v2.x) + bfhi(v3.x)
                  + bfhi(v4.x) + bfhi(v5.x) + bfhi(v6.x) + bfhi(v7.x);
            a0.z += bflo(v0.y) + bflo(v1.y) + bflo(v2.y) + bflo(v3.y)
                  + bflo(v4.y) + bflo(v5.y) + bflo(v6.y) + bflo(v7.y);
            a0.w += bfhi(v0.y) + bfhi(v1.y) + bfhi(v2.y) + bfhi(v3.y)
                  + bfhi(v4.y) + bfhi(v5.y) + bfhi(v6.y) + bfhi(v7.y);
            a1.x += bflo(v0.z) + bflo(v1.z) + bflo(v2.z) + bflo(v3.z)
                  + bflo(v4.z) + bflo(v5.z) + bflo(v6.z) + bflo(v7.z);
            a1.y += bfhi(v0.z) + bfhi(v1.z) + bfhi(v2.z) + bfhi(v3.z)
                  + bfhi(v4.z) + bfhi(v5.z) + bfhi(v6.z) + bfhi(v7.z);
            a1.z += bflo(v0.w) + bflo(v1.w) + bflo(v2.w) + bflo(v3.w)
                  + bflo(v4.w) + bflo(v5.w) + bflo(v6.w) + bflo(v7.w);
            a1.w += bfhi(v0.w) + bfhi(v1.w) + bfhi(v2.w) + bfhi(v3.w)
                  + bfhi(v4.w) + bfhi(v5.w) + bfhi(v6.w) + bfhi(v7.w);
        }
        for (; j < end; ++j) {
            int s = csr_src[j];
            uint4 v = ((const uint4*)(tb + (size_t)s * 32))[l4];
            a0.x += bflo(v.x); a0.y += bfhi(v.x); a0.z += bflo(v.y); a0.w += bfhi(v.y);
            a1.x += bflo(v.z); a1.y += bfhi(v.z); a1.z += bflo(v.w); a1.w += bfhi(v.w);
        }
        float dv = dinv[node];
        r0.x = a0.x * dv; r0.y = a0.y * dv; r0.z = a0.z * dv; r0.w = a0.w * dv;
        r1.x = a1.x * dv; r1.y = a1.y * dv; r1.z = a1.z * dv; r1.w = a1.w * dv;
        float4* ar = (float4*)(agg + (size_t)node * HID + plane * 32);
        ar[l4 * 2 + 0] = r0;
        ar[l4 * 2 + 1] = r1;
    }

    float4 q0, q1;
    q0.x = r0.x * r0.x; q0.y = r0.y * r0.y; q0.z = r0.z * r0.z; q0.w = r0.w * r0.w;
    q1.x = r1.x * r1.x; q1.y = r1.y * r1.y; q1.z = r1.z * r1.z; q1.w = r1.w * r1.w;
#pragma unroll
    for (int off = 4; off < 64; off <<= 1) {
        r0.x += __shfl_xor(r0.x, off, 64); q0.x += __shfl_xor(q0.x, off, 64);
        r0.y += __shfl_xor(r0.y, off, 64); q0.y += __shfl_xor(q0.y, off, 64);
        r0.z += __shfl_xor(r0.z, off, 64); q0.z += __shfl_xor(q0.z, off, 64);
        r0.w += __shfl_xor(r0.w, off, 64); q0.w += __shfl_xor(q0.w, off, 64);
        r1.x += __shfl_xor(r1.x, off, 64); q1.x += __shfl_xor(q1.x, off, 64);
        r1.y += __shfl_xor(r1.y, off, 64); q1.y += __shfl_xor(q1.y, off, 64);
        r1.z += __shfl_xor(r1.z, off, 64); q1.z += __shfl_xor(q1.z, off, 64);
        r1.w += __shfl_xor(r1.w, off, 64); q1.w += __shfl_xor(q1.w, off, 64);
    }
    if ((threadIdx.x & 63) < 4) {
        int f0 = plane * 32 + l4 * 8;
        atomicAdd(&lsum[f0 + 0], r0.x); atomicAdd(&lsq[f0 + 0], q0.x);
        atomicAdd(&lsum[f0 + 1], r0.y); atomicAdd(&lsq[f0 + 1], q0.y);
        atomicAdd(&lsum[f0 + 2], r0.z); atomicAdd(&lsq[f0 + 2], q0.z);
        atomicAdd(&lsum[f0 + 3], r0.w); atomicAdd(&lsq[f0 + 3], q0.w);
        atomicAdd(&lsum[f0 + 4], r1.x); atomicAdd(&lsq[f0 + 4], q1.x);
        atomicAdd(&lsum[f0 + 5], r1.y); atomicAdd(&lsq[f0 + 5], q1.y);
        atomicAdd(&lsum[f0 + 6], r1.z); atomicAdd(&lsq[f0 + 6], q1.z);
        atomicAdd(&lsum[f0 + 7], r1.w); atomicAdd(&lsq[f0 + 7], q1.w);
    }
    __syncthreads();
    int fs = plane * 32 + (threadIdx.x & 31);
    if (threadIdx.x < 32) {
        atomicAdd(&stats[fs], lsum[fs]);
        atomicAdd(&stats[HID + fs], lsq[fs]);
    }
}

// final: h = relu(bn(agg)) + h
__global__ __launch_bounds__(256) void k_bn_apply(const float* __restrict__ agg,
                                                  const float* __restrict__ stats,
                                                  const float* __restrict__ gamma,
                                                  const float* __restrict__ beta,
                                                  float* __restrict__ h, int n, float invN) {
    int gid = blockIdx.x * blockDim.x + threadIdx.x;
    int node = gid >> 6, f = gid & 63;
    if (node >= n) return;
    float mu = stats[f] * invN;
    float var = fmaxf(stats[HID + f] * invN - mu * mu, 0.0f);
    float bn = (agg[gid] - mu) * rsqrtf(var + BN_EPS) * gamma[f] + beta[f];
    h[gid] = fmaxf(bn, 0.0f) + h[gid];
}

extern "C" void kernel_launch(void* const* d_in, const int* in_sizes, int n_in,
                              void* d_out, int out_size, void* d_ws, size_t ws_size,
                              hipStream_t stream) {
    const float* x       = (const float*)d_in[0];
    const int*   ei      = (const int*)d_in[1];
    const float* W_embed = (const float*)d_in[2];
    const float* b_embed = (const float*)d_in[3];
    const float* W_convs = (const float*)d_in[4];
    const float* b_convs = (const float*)d_in[5];
    const float* gamma   = (const float*)d_in[6];
    const float* beta    = (const float*)d_in[7];
    float* h = (float*)d_out;

    const int n = in_sizes[0] / IN_F;   // 50000
    const int e = in_sizes[1] / 2;      // 800000
    const int* src = ei;
    const int* dst = ei + e;

    unsigned short* t2b = (unsigned short*)d_ws;            // 2 planes * n*32 bf16
    float* agg      = (float*)(t2b + (size_t)n * HID);      // n*HID f32
    float* dinv     = agg + (size_t)n * HID;                // n
    float* statsAll = dinv + n;                             // 3*128
    int*   rowbeg   = (int*)(statsAll + 2 * HID * N_LAYERS);// n
    int*   cnt      = rowbeg + n;                           // n
    int*   cursor   = cnt + n;                              // 1
    unsigned short* csr_src = (unsigned short*)(cursor + 1);// e
    unsigned short* rank    = csr_src + e;                  // e

    const int nodeBlocks  = (n + 255) / 256;
    const int nfBlocks    = (n * HID + 255) / 256;
    const int edgeBlocks  = (e + 255) / 256;
    const int aggBlocks   = ((n + 63) / 64) * 2;   // 1-D: plane = bid&1 (XCD parity)
    const int denseBlocks = (n + 16 * 4 - 1) / (16 * 4);   // 782: 4 waves/blk, 16 nodes/wave

    k_zero<<<nodeBlocks, 256, 0, stream>>>(cnt, cursor, statsAll, n);
    k_hist_rank<<<edgeBlocks, 256, 0, stream>>>(dst, cnt, rank, e);
    k_assign<<<nodeBlocks, 256, 0, stream>>>(cnt, rowbeg, dinv, cursor, n);
    k_fill<<<edgeBlocks, 256, 0, stream>>>(src, dst, rowbeg, rank, csr_src, e);

    const float invN = 1.0f / (float)n;

    k_embed_conv<<<denseBlocks, 256, 0, stream>>>(x, W_embed, b_embed, W_convs, b_convs,
                                                  dinv, h, t2b, n);

    for (int l = 0; l < N_LAYERS; ++l) {
        float* stats = statsAll + (size_t)l * 2 * HID;
        k_aggregate<<<aggBlocks, 256, 0, stream>>>(rowbeg, cnt, csr_src, t2b, dinv,
                                                   agg, stats, n);
        if (l < N_LAYERS - 1) {
            const float* Wl = W_convs + (size_t)(l + 1) * HID * HID;
            const float* bl = b_convs + (size_t)(l + 1) * HID;
            k_bn_conv<<<denseBlocks, 256, 0, stream>>>(agg, stats, gamma, beta, Wl, bl, dinv,
                                                       h, t2b, n, invN);
        } else {
            k_bn_apply<<<nfBlocks, 256, 0, stream>>>(agg, stats, gamma, beta, h, n, invN);
        }
    }
}

// Round 11
// 233.077 us; speedup vs baseline: 1.5397x; 1.5397x over previous
//
#include <hip/hip_runtime.h>

#define IN_F 32
#define HID 64
#define N_LAYERS 3
#define BN_EPS 1e-5f

__device__ __forceinline__ unsigned short f2bf(float x) {
    unsigned u = __float_as_uint(x);
    u += 0x7fffu + ((u >> 16) & 1u);
    return (unsigned short)(u >> 16);
}
__device__ __forceinline__ float bflo(unsigned v) { return __uint_as_float(v << 16); }
__device__ __forceinline__ float bfhi(unsigned v) { return __uint_as_float(v & 0xffff0000u); }

// ---------------- CSR build ----------------
__global__ __launch_bounds__(256) void k_zero(int* cnt, int* cursor, float* statsAll, int n) {
    int i = blockIdx.x * blockDim.x + threadIdx.x;
    if (i < n) cnt[i] = 0;
    if (i == 0) *cursor = 0;
    if (i < 2 * HID * N_LAYERS) statsAll[i] = 0.0f;
}

__global__ __launch_bounds__(256) void k_hist_rank(const int* __restrict__ dst, int* cnt,
                                                   unsigned short* __restrict__ rank, int e) {
    int i = blockIdx.x * blockDim.x + threadIdx.x;
    if (i >= e) return;
    int r = atomicAdd(&cnt[dst[i]], 1);
    rank[i] = (unsigned short)r;
}

__global__ __launch_bounds__(256) void k_assign(const int* __restrict__ cnt, int* rowbeg,
                                                float* dinv, int* cursor, int n) {
    int i = blockIdx.x * blockDim.x + threadIdx.x;
    int lane = threadIdx.x & 63;
    int c = (i < n) ? cnt[i] : 0;
    int s = c;
#pragma unroll
    for (int off = 1; off < 64; off <<= 1) {
        int t = __shfl_up(s, off, 64);
        if (lane >= off) s += t;
    }
    int total = __shfl(s, 63, 64);
    int base = 0;
    if (lane == 63) base = atomicAdd(cursor, total);
    base = __shfl(base, 63, 64);
    if (i < n) {
        rowbeg[i] = base + s - c;
        dinv[i] = rsqrtf((float)(c + 1));
    }
}

__global__ __launch_bounds__(256) void k_fill(const int* __restrict__ src,
                                              const int* __restrict__ dst,
                                              const int* __restrict__ rowbeg,
                                              const unsigned short* __restrict__ rank,
                                              unsigned short* __restrict__ csr_src, int e) {
    int i = blockIdx.x * blockDim.x + threadIdx.x;
    if (i >= e) return;
    int pos = rowbeg[dst[i]] + (int)rank[i];
    csr_src[pos] = (unsigned short)src[i];
}

// ---------------- fused dense ops: register-resident W, wave = node ----------------
// Lane f holds W column f in registers (we[32], wc[64]); row operands come from
// tiny wave-private LDS via same-address (broadcast) ds_read_b128 -- conflict-free.
__global__ __launch_bounds__(256, 4) void k_embed_conv(const float* __restrict__ x,
                                                       const float* __restrict__ We,
                                                       const float* __restrict__ be,
                                                       const float* __restrict__ Wc,
                                                       const float* __restrict__ bc,
                                                       const float* __restrict__ dinv,
                                                       float* __restrict__ h,
                                                       unsigned short* __restrict__ t2b, int n) {
    __shared__ float shx[4][IN_F];   // per-wave x row
    __shared__ float shh[4][HID];    // per-wave h row
    int f = threadIdx.x & 63;
    int wv = threadIdx.x >> 6;
    int plane = f >> 5, fin = f & 31;

    float we[IN_F];
#pragma unroll
    for (int k = 0; k < IN_F; ++k) we[k] = We[k * HID + f];
    float wc[HID];
#pragma unroll
    for (int k = 0; k < HID; ++k) wc[k] = Wc[k * HID + f];
    float bef = be[f], bcf = bc[f];

    int nw = gridDim.x * 4;
    for (int node = blockIdx.x * 4 + wv; node < n; node += nw) {
        if (f < IN_F) shx[wv][f] = x[(size_t)node * IN_F + f];
        float acc = bef;
#pragma unroll
        for (int k4 = 0; k4 < IN_F / 4; ++k4) {
            float4 xq = ((const float4*)shx[wv])[k4];   // broadcast read
            acc = fmaf(xq.x, we[k4 * 4 + 0], acc);
            acc = fmaf(xq.y, we[k4 * 4 + 1], acc);
            acc = fmaf(xq.z, we[k4 * 4 + 2], acc);
            acc = fmaf(xq.w, we[k4 * 4 + 3], acc);
        }
        float hv = fmaxf(acc, 0.0f);
        h[(size_t)node * HID + f] = hv;
        shh[wv][f] = hv;
        float acc2 = bcf;
#pragma unroll
        for (int k4 = 0; k4 < HID / 4; ++k4) {
            float4 hq = ((const float4*)shh[wv])[k4];   // broadcast read
            acc2 = fmaf(hq.x, wc[k4 * 4 + 0], acc2);
            acc2 = fmaf(hq.y, wc[k4 * 4 + 1], acc2);
            acc2 = fmaf(hq.z, wc[k4 * 4 + 2], acc2);
            acc2 = fmaf(hq.w, wc[k4 * 4 + 3], acc2);
        }
        t2b[(size_t)plane * n * 32 + (size_t)node * 32 + fin] = f2bf(acc2 * dinv[node]);
    }
}

__global__ __launch_bounds__(256, 4) void k_bn_conv(const float* __restrict__ agg,
                                                    const float* __restrict__ stats,
                                                    const float* __restrict__ gamma,
                                                    const float* __restrict__ beta,
                                                    const float* __restrict__ W,
                                                    const float* __restrict__ b,
                                                    const float* __restrict__ dinv,
                                                    float* __restrict__ h,
                                                    unsigned short* __restrict__ t2b, int n, float invN) {
    __shared__ float shh[4][HID];
    int f = threadIdx.x & 63;
    int wv = threadIdx.x >> 6;
    int plane = f >> 5, fin = f & 31;

    float wc[HID];
#pragma unroll
    for (int k = 0; k < HID; ++k) wc[k] = W[k * HID + f];

    float mu = stats[f] * invN;
    float var = fmaxf(stats[HID + f] * invN - mu * mu, 0.0f);
    float scale = rsqrtf(var + BN_EPS) * gamma[f];
    float shift = beta[f];
    float bf = b[f];

    int nw = gridDim.x * 4;
    for (int node = blockIdx.x * 4 + wv; node < n; node += nw) {
        size_t gid = (size_t)node * HID + f;
        float bnv = (agg[gid] - mu) * scale + shift;
        float hv = fmaxf(bnv, 0.0f) + h[gid];
        h[gid] = hv;
        shh[wv][f] = hv;
        float acc = bf;
#pragma unroll
        for (int k4 = 0; k4 < HID / 4; ++k4) {
            float4 hq = ((const float4*)shh[wv])[k4];   // broadcast read
            acc = fmaf(hq.x, wc[k4 * 4 + 0], acc);
            acc = fmaf(hq.y, wc[k4 * 4 + 1], acc);
            acc = fmaf(hq.z, wc[k4 * 4 + 2], acc);
            acc = fmaf(hq.w, wc[k4 * 4 + 3], acc);
        }
        t2b[(size_t)plane * n * 32 + (size_t)node * 32 + fin] = f2bf(acc * dinv[node]);
    }
}

// one 4-lane group per node per plane; 1-D grid, plane = blockIdx.x & 1 (XCD parity:
// each XCD's L2 holds ONE 3.2 MB plane table).
__global__ __launch_bounds__(256) void k_aggregate(const int* __restrict__ rowbeg,
                                                   const int* __restrict__ cnt,
                                                   const unsigned short* __restrict__ csr_src,
                                                   const unsigned short* __restrict__ t2b,
                                                   const float* __restrict__ dinv,
                                                   float* __restrict__ agg,
                                                   float* __restrict__ stats, int n) {
    __shared__ float lsum[HID], lsq[HID];
    if (threadIdx.x < HID) { lsum[threadIdx.x] = 0.0f; lsq[threadIdx.x] = 0.0f; }
    __syncthreads();

    const int plane = blockIdx.x & 1;
    const unsigned short* tb = t2b + (size_t)plane * n * 32;

    int l4 = threadIdx.x & 3;
    int node = (blockIdx.x >> 1) * 64 + (threadIdx.x >> 2);

    float4 r0 = make_float4(0.f, 0.f, 0.f, 0.f);
    float4 r1 = make_float4(0.f, 0.f, 0.f, 0.f);

    if (node < n) {
        int beg = rowbeg[node], end = beg + cnt[node];
        uint4 sv = ((const uint4*)(tb + (size_t)node * 32))[l4];
        float4 a0, a1;
        a0.x = bflo(sv.x); a0.y = bfhi(sv.x); a0.z = bflo(sv.y); a0.w = bfhi(sv.y);
        a1.x = bflo(sv.z); a1.y = bfhi(sv.z); a1.z = bflo(sv.w); a1.w = bfhi(sv.w);
        int j = beg;
        for (; j + 8 <= end; j += 8) {
            int s0 = csr_src[j + 0], s1 = csr_src[j + 1];
            int s2 = csr_src[j + 2], s3 = csr_src[j + 3];
            int s4 = csr_src[j + 4], s5 = csr_src[j + 5];
            int s6 = csr_src[j + 6], s7 = csr_src[j + 7];
            uint4 v0 = ((const uint4*)(tb + (size_t)s0 * 32))[l4];
            uint4 v1 = ((const uint4*)(tb + (size_t)s1 * 32))[l4];
            uint4 v2 = ((const uint4*)(tb + (size_t)s2 * 32))[l4];
            uint4 v3 = ((const uint4*)(tb + (size_t)s3 * 32))[l4];
            uint4 v4 = ((const uint4*)(tb + (size_t)s4 * 32))[l4];
            uint4 v5 = ((const uint4*)(tb + (size_t)s5 * 32))[l4];
            uint4 v6 = ((const uint4*)(tb + (size_t)s6 * 32))[l4];
            uint4 v7 = ((const uint4*)(tb + (size_t)s7 * 32))[l4];
            a0.x += bflo(v0.x) + bflo(v1.x) + bflo(v2.x) + bflo(v3.x)
                  + bflo(v4.x) + bflo(v5.x) + bflo(v6.x) + bflo(v7.x);
            a0.y += bfhi(v0.x) + bfhi(v1.x) + bfhi(v2.x) + bfhi(v3.x)
                  + bfhi(v4.x) + bfhi(v5.x) + bfhi(v6.x) + bfhi(v7.x);
            a0.z += bflo(v0.y) + bflo(v1.y) + bflo(v2.y) + bflo(v3.y)
                  + bflo(v4.y) + bflo(v5.y) + bflo(v6.y) + bflo(v7.y);
            a0.w += bfhi(v0.y) + bfhi(v1.y) + bfhi(v2.y) + bfhi(v3.y)
                  + bfhi(v4.y) + bfhi(v5.y) + bfhi(v6.y) + bfhi(v7.y);
            a1.x += bflo(v0.z) + bflo(v1.z) + bflo(v2.z) + bflo(v3.z)
                  + bflo(v4.z) + bflo(v5.z) + bflo(v6.z) + bflo(v7.z);
            a1.y += bfhi(v0.z) + bfhi(v1.z) + bfhi(v2.z) + bfhi(v3.z)
                  + bfhi(v4.z) + bfhi(v5.z) + bfhi(v6.z) + bfhi(v7.z);
            a1.z += bflo(v0.w) + bflo(v1.w) + bflo(v2.w) + bflo(v3.w)
                  + bflo(v4.w) + bflo(v5.w) + bflo(v6.w) + bflo(v7.w);
            a1.w += bfhi(v0.w) + bfhi(v1.w) + bfhi(v2.w) + bfhi(v3.w)
                  + bfhi(v4.w) + bfhi(v5.w) + bfhi(v6.w) + bfhi(v7.w);
        }
        for (; j < end; ++j) {
            int s = csr_src[j];
            uint4 v = ((const uint4*)(tb + (size_t)s * 32))[l4];
            a0.x += bflo(v.x); a0.y += bfhi(v.x); a0.z += bflo(v.y); a0.w += bfhi(v.y);
            a1.x += bflo(v.z); a1.y += bfhi(v.z); a1.z += bflo(v.w); a1.w += bfhi(v.w);
        }
        float dv = dinv[node];
        r0.x = a0.x * dv; r0.y = a0.y * dv; r0.z = a0.z * dv; r0.w = a0.w * dv;
        r1.x = a1.x * dv; r1.y = a1.y * dv; r1.z = a1.z * dv; r1.w = a1.w * dv;
        float4* ar = (float4*)(agg + (size_t)node * HID + plane * 32);
        ar[l4 * 2 + 0] = r0;
        ar[l4 * 2 + 1] = r1;
    }

    float4 q0, q1;
    q0.x = r0.x * r0.x; q0.y = r0.y * r0.y; q0.z = r0.z * r0.z; q0.w = r0.w * r0.w;
    q1.x = r1.x * r1.x; q1.y = r1.y * r1.y; q1.z = r1.z * r1.z; q1.w = r1.w * r1.w;
#pragma unroll
    for (int off = 4; off < 64; off <<= 1) {
        r0.x += __shfl_xor(r0.x, off, 64); q0.x += __shfl_xor(q0.x, off, 64);
        r0.y += __shfl_xor(r0.y, off, 64); q0.y += __shfl_xor(q0.y, off, 64);
        r0.z += __shfl_xor(r0.z, off, 64); q0.z += __shfl_xor(q0.z, off, 64);
        r0.w += __shfl_xor(r0.w, off, 64); q0.w += __shfl_xor(q0.w, off, 64);
        r1.x += __shfl_xor(r1.x, off, 64); q1.x += __shfl_xor(q1.x, off, 64);
        r1.y += __shfl_xor(r1.y, off, 64); q1.y += __shfl_xor(q1.y, off, 64);
        r1.z += __shfl_xor(r1.z, off, 64); q1.z += __shfl_xor(q1.z, off, 64);
        r1.w += __shfl_xor(r1.w, off, 64); q1.w += __shfl_xor(q1.w, off, 64);
    }
    if ((threadIdx.x & 63) < 4) {
        int f0 = plane * 32 + l4 * 8;
        atomicAdd(&lsum[f0 + 0], r0.x); atomicAdd(&lsq[f0 + 0], q0.x);
        atomicAdd(&lsum[f0 + 1], r0.y); atomicAdd(&lsq[f0 + 1], q0.y);
        atomicAdd(&lsum[f0 + 2], r0.z); atomicAdd(&lsq[f0 + 2], q0.z);
        atomicAdd(&lsum[f0 + 3], r0.w); atomicAdd(&lsq[f0 + 3], q0.w);
        atomicAdd(&lsum[f0 + 4], r1.x); atomicAdd(&lsq[f0 + 4], q1.x);
        atomicAdd(&lsum[f0 + 5], r1.y); atomicAdd(&lsq[f0 + 5], q1.y);
        atomicAdd(&lsum[f0 + 6], r1.z); atomicAdd(&lsq[f0 + 6], q1.z);
        atomicAdd(&lsum[f0 + 7], r1.w); atomicAdd(&lsq[f0 + 7], q1.w);
    }
    __syncthreads();
    int fs = plane * 32 + (threadIdx.x & 31);
    if (threadIdx.x < 32) {
        atomicAdd(&stats[fs], lsum[fs]);
        atomicAdd(&stats[HID + fs], lsq[fs]);
    }
}

// final: h = relu(bn(agg)) + h
__global__ __launch_bounds__(256) void k_bn_apply(const float* __restrict__ agg,
                                                  const float* __restrict__ stats,
                                                  const float* __restrict__ gamma,
                                                  const float* __restrict__ beta,
                                                  float* __restrict__ h, int n, float invN) {
    int gid = blockIdx.x * blockDim.x + threadIdx.x;
    int node = gid >> 6, f = gid & 63;
    if (node >= n) return;
    float mu = stats[f] * invN;
    float var = fmaxf(stats[HID + f] * invN - mu * mu, 0.0f);
    float bn = (agg[gid] - mu) * rsqrtf(var + BN_EPS) * gamma[f] + beta[f];
    h[gid] = fmaxf(bn, 0.0f) + h[gid];
}

extern "C" void kernel_launch(void* const* d_in, const int* in_sizes, int n_in,
                              void* d_out, int out_size, void* d_ws, size_t ws_size,
                              hipStream_t stream) {
    const float* x       = (const float*)d_in[0];
    const int*   ei      = (const int*)d_in[1];
    const float* W_embed = (const float*)d_in[2];
    const float* b_embed = (const float*)d_in[3];
    const float* W_convs = (const float*)d_in[4];
    const float* b_convs = (const float*)d_in[5];
    const float* gamma   = (const float*)d_in[6];
    const float* beta    = (const float*)d_in[7];
    float* h = (float*)d_out;

    const int n = in_sizes[0] / IN_F;   // 50000
    const int e = in_sizes[1] / 2;      // 800000
    const int* src = ei;
    const int* dst = ei + e;

    unsigned short* t2b = (unsigned short*)d_ws;            // 2 planes * n*32 bf16
    float* agg      = (float*)(t2b + (size_t)n * HID);      // n*HID f32
    float* dinv     = agg + (size_t)n * HID;                // n
    float* statsAll = dinv + n;                             // 3*128
    int*   rowbeg   = (int*)(statsAll + 2 * HID * N_LAYERS);// n
    int*   cnt      = rowbeg + n;                           // n
    int*   cursor   = cnt + n;                              // 1
    unsigned short* csr_src = (unsigned short*)(cursor + 1);// e
    unsigned short* rank    = csr_src + e;                  // e

    const int nodeBlocks  = (n + 255) / 256;
    const int nfBlocks    = (n * HID + 255) / 256;
    const int edgeBlocks  = (e + 255) / 256;
    const int aggBlocks   = ((n + 63) / 64) * 2;   // 1-D: plane = bid&1 (XCD parity)
    const int denseBlocks = 1024;                  // grid-stride, 4 nodes/block/iter

    k_zero<<<nodeBlocks, 256, 0, stream>>>(cnt, cursor, statsAll, n);
    k_hist_rank<<<edgeBlocks, 256, 0, stream>>>(dst, cnt, rank, e);
    k_assign<<<nodeBlocks, 256, 0, stream>>>(cnt, rowbeg, dinv, cursor, n);
    k_fill<<<edgeBlocks, 256, 0, stream>>>(src, dst, rowbeg, rank, csr_src, e);

    const float invN = 1.0f / (float)n;

    k_embed_conv<<<denseBlocks, 256, 0, stream>>>(x, W_embed, b_embed, W_convs, b_convs,
                                                  dinv, h, t2b, n);

    for (int l = 0; l < N_LAYERS; ++l) {
        float* stats = statsAll + (size_t)l * 2 * HID;
        k_aggregate<<<aggBlocks, 256, 0, stream>>>(rowbeg, cnt, csr_src, t2b, dinv,
                                                   agg, stats, n);
        if (l < N_LAYERS - 1) {
            const float* Wl = W_convs + (size_t)(l + 1) * HID * HID;
            const float* bl = b_convs + (size_t)(l + 1) * HID;
            k_bn_conv<<<denseBlocks, 256, 0, stream>>>(agg, stats, gamma, beta, Wl, bl, dinv,
                                                       h, t2b, n, invN);
        } else {
            k_bn_apply<<<nfBlocks, 256, 0, stream>>>(agg, stats, gamma, beta, h, n, invN);
        }
    }
}

// Round 12
// 218.185 us; speedup vs baseline: 1.6448x; 1.0683x over previous
//
#include <hip/hip_runtime.h>

#define IN_F 32
#define HID 64
#define N_LAYERS 3
#define BN_EPS 1e-5f
#define NPLANE 4
#define PF 16   // features per plane

__device__ __forceinline__ unsigned short f2bf(float x) {
    unsigned u = __float_as_uint(x);
    u += 0x7fffu + ((u >> 16) & 1u);
    return (unsigned short)(u >> 16);
}
__device__ __forceinline__ float bflo(unsigned v) { return __uint_as_float(v << 16); }
__device__ __forceinline__ float bfhi(unsigned v) { return __uint_as_float(v & 0xffff0000u); }

// ---------------- CSR build ----------------
__global__ __launch_bounds__(256) void k_zero(int* cnt, int* cursor, float* statsAll, int n) {
    int i = blockIdx.x * blockDim.x + threadIdx.x;
    if (i < n) cnt[i] = 0;
    if (i == 0) *cursor = 0;
    if (i < 2 * HID * N_LAYERS) statsAll[i] = 0.0f;
}

__global__ __launch_bounds__(256) void k_hist_rank(const int* __restrict__ dst, int* cnt,
                                                   unsigned short* __restrict__ rank, int e) {
    int i = blockIdx.x * blockDim.x + threadIdx.x;
    if (i >= e) return;
    int r = atomicAdd(&cnt[dst[i]], 1);
    rank[i] = (unsigned short)r;
}

__global__ __launch_bounds__(256) void k_assign(const int* __restrict__ cnt, int* rowbeg,
                                                float* dinv, int* cursor, int n) {
    int i = blockIdx.x * blockDim.x + threadIdx.x;
    int lane = threadIdx.x & 63;
    int c = (i < n) ? cnt[i] : 0;
    int s = c;
#pragma unroll
    for (int off = 1; off < 64; off <<= 1) {
        int t = __shfl_up(s, off, 64);
        if (lane >= off) s += t;
    }
    int total = __shfl(s, 63, 64);
    int base = 0;
    if (lane == 63) base = atomicAdd(cursor, total);
    base = __shfl(base, 63, 64);
    if (i < n) {
        rowbeg[i] = base + s - c;
        dinv[i] = rsqrtf((float)(c + 1));
    }
}

__global__ __launch_bounds__(256) void k_fill(const int* __restrict__ src,
                                              const int* __restrict__ dst,
                                              const int* __restrict__ rowbeg,
                                              const unsigned short* __restrict__ rank,
                                              unsigned short* __restrict__ csr_src, int e) {
    int i = blockIdx.x * blockDim.x + threadIdx.x;
    if (i >= e) return;
    int pos = rowbeg[dst[i]] + (int)rank[i];
    csr_src[pos] = (unsigned short)src[i];
}

// ---------------- fused dense ops: register-resident W, wave = node ----------------
__global__ __launch_bounds__(256, 4) void k_embed_conv(const float* __restrict__ x,
                                                       const float* __restrict__ We,
                                                       const float* __restrict__ be,
                                                       const float* __restrict__ Wc,
                                                       const float* __restrict__ bc,
                                                       const float* __restrict__ dinv,
                                                       float* __restrict__ h,
                                                       unsigned short* __restrict__ t2b, int n) {
    __shared__ float shx[4][IN_F];
    __shared__ float shh[4][HID];
    int f = threadIdx.x & 63;
    int wv = threadIdx.x >> 6;
    int plane = f >> 4, fin = f & 15;

    float we[IN_F];
#pragma unroll
    for (int k = 0; k < IN_F; ++k) we[k] = We[k * HID + f];
    float wc[HID];
#pragma unroll
    for (int k = 0; k < HID; ++k) wc[k] = Wc[k * HID + f];
    float bef = be[f], bcf = bc[f];

    int nw = gridDim.x * 4;
    for (int node = blockIdx.x * 4 + wv; node < n; node += nw) {
        if (f < IN_F) shx[wv][f] = x[(size_t)node * IN_F + f];
        float acc = bef;
#pragma unroll
        for (int k4 = 0; k4 < IN_F / 4; ++k4) {
            float4 xq = ((const float4*)shx[wv])[k4];
            acc = fmaf(xq.x, we[k4 * 4 + 0], acc);
            acc = fmaf(xq.y, we[k4 * 4 + 1], acc);
            acc = fmaf(xq.z, we[k4 * 4 + 2], acc);
            acc = fmaf(xq.w, we[k4 * 4 + 3], acc);
        }
        float hv = fmaxf(acc, 0.0f);
        h[(size_t)node * HID + f] = hv;
        shh[wv][f] = hv;
        float acc2 = bcf;
#pragma unroll
        for (int k4 = 0; k4 < HID / 4; ++k4) {
            float4 hq = ((const float4*)shh[wv])[k4];
            acc2 = fmaf(hq.x, wc[k4 * 4 + 0], acc2);
            acc2 = fmaf(hq.y, wc[k4 * 4 + 1], acc2);
            acc2 = fmaf(hq.z, wc[k4 * 4 + 2], acc2);
            acc2 = fmaf(hq.w, wc[k4 * 4 + 3], acc2);
        }
        t2b[(size_t)plane * n * PF + (size_t)node * PF + fin] = f2bf(acc2 * dinv[node]);
    }
}

__global__ __launch_bounds__(256, 4) void k_bn_conv(const float* __restrict__ agg,
                                                    const float* __restrict__ stats,
                                                    const float* __restrict__ gamma,
                                                    const float* __restrict__ beta,
                                                    const float* __restrict__ W,
                                                    const float* __restrict__ b,
                                                    const float* __restrict__ dinv,
                                                    float* __restrict__ h,
                                                    unsigned short* __restrict__ t2b, int n, float invN) {
    __shared__ float shh[4][HID];
    int f = threadIdx.x & 63;
    int wv = threadIdx.x >> 6;
    int plane = f >> 4, fin = f & 15;

    float wc[HID];
#pragma unroll
    for (int k = 0; k < HID; ++k) wc[k] = W[k * HID + f];

    float mu = stats[f] * invN;
    float var = fmaxf(stats[HID + f] * invN - mu * mu, 0.0f);
    float scale = rsqrtf(var + BN_EPS) * gamma[f];
    float shift = beta[f];
    float bf = b[f];

    int nw = gridDim.x * 4;
    for (int node = blockIdx.x * 4 + wv; node < n; node += nw) {
        size_t gid = (size_t)node * HID + f;
        float bnv = (agg[gid] - mu) * scale + shift;
        float hv = fmaxf(bnv, 0.0f) + h[gid];
        h[gid] = hv;
        shh[wv][f] = hv;
        float acc = bf;
#pragma unroll
        for (int k4 = 0; k4 < HID / 4; ++k4) {
            float4 hq = ((const float4*)shh[wv])[k4];
            acc = fmaf(hq.x, wc[k4 * 4 + 0], acc);
            acc = fmaf(hq.y, wc[k4 * 4 + 1], acc);
            acc = fmaf(hq.z, wc[k4 * 4 + 2], acc);
            acc = fmaf(hq.w, wc[k4 * 4 + 3], acc);
        }
        t2b[(size_t)plane * n * PF + (size_t)node * PF + fin] = f2bf(acc * dinv[node]);
    }
}

// one 2-lane group per node per plane; plane = blockIdx.x & 3 -> XCD k serves plane k&3
// (per-XCD random working set = 1.6 MB, fits L2 with room to spare).
__global__ __launch_bounds__(256) void k_aggregate(const int* __restrict__ rowbeg,
                                                   const int* __restrict__ cnt,
                                                   const unsigned short* __restrict__ csr_src,
                                                   const unsigned short* __restrict__ t2b,
                                                   const float* __restrict__ dinv,
                                                   float* __restrict__ agg,
                                                   float* __restrict__ stats, int n) {
    __shared__ float lsum[PF], lsq[PF];
    if (threadIdx.x < PF) { lsum[threadIdx.x] = 0.0f; lsq[threadIdx.x] = 0.0f; }
    __syncthreads();

    const int plane = blockIdx.x & 3;
    const unsigned short* tb = t2b + (size_t)plane * n * PF;

    int l2 = threadIdx.x & 1;                         // half-row (8 feats = 16 B)
    int node = (blockIdx.x >> 2) * 128 + (threadIdx.x >> 1);

    float4 r0 = make_float4(0.f, 0.f, 0.f, 0.f);
    float4 r1 = make_float4(0.f, 0.f, 0.f, 0.f);

    if (node < n) {
        int beg = rowbeg[node], end = beg + cnt[node];
        uint4 sv = ((const uint4*)(tb + (size_t)node * PF))[l2];
        float4 a0, a1;
        a0.x = bflo(sv.x); a0.y = bfhi(sv.x); a0.z = bflo(sv.y); a0.w = bfhi(sv.y);
        a1.x = bflo(sv.z); a1.y = bfhi(sv.z); a1.z = bflo(sv.w); a1.w = bfhi(sv.w);
        int j = beg;
        for (; j + 8 <= end; j += 8) {
            int s0 = csr_src[j + 0], s1 = csr_src[j + 1];
            int s2 = csr_src[j + 2], s3 = csr_src[j + 3];
            int s4 = csr_src[j + 4], s5 = csr_src[j + 5];
            int s6 = csr_src[j + 6], s7 = csr_src[j + 7];
            uint4 v0 = ((const uint4*)(tb + (size_t)s0 * PF))[l2];
            uint4 v1 = ((const uint4*)(tb + (size_t)s1 * PF))[l2];
            uint4 v2 = ((const uint4*)(tb + (size_t)s2 * PF))[l2];
            uint4 v3 = ((const uint4*)(tb + (size_t)s3 * PF))[l2];
            uint4 v4 = ((const uint4*)(tb + (size_t)s4 * PF))[l2];
            uint4 v5 = ((const uint4*)(tb + (size_t)s5 * PF))[l2];
            uint4 v6 = ((const uint4*)(tb + (size_t)s6 * PF))[l2];
            uint4 v7 = ((const uint4*)(tb + (size_t)s7 * PF))[l2];
            a0.x += bflo(v0.x) + bflo(v1.x) + bflo(v2.x) + bflo(v3.x)
                  + bflo(v4.x) + bflo(v5.x) + bflo(v6.x) + bflo(v7.x);
            a0.y += bfhi(v0.x) + bfhi(v1.x) + bfhi(v2.x) + bfhi(v3.x)
                  + bfhi(v4.x) + bfhi(v5.x) + bfhi(v6.x) + bfhi(v7.x);
            a0.z += bflo(v0.y) + bflo(v1.y) + bflo(v2.y) + bflo(v3.y)
                  + bflo(v4.y) + bflo(v5.y) + bflo(v6.y) + bflo(v7.y);
            a0.w += bfhi(v0.y) + bfhi(v1.y) + bfhi(v2.y) + bfhi(v3.y)
                  + bfhi(v4.y) + bfhi(v5.y) + bfhi(v6.y) + bfhi(v7.y);
            a1.x += bflo(v0.z) + bflo(v1.z) + bflo(v2.z) + bflo(v3.z)
                  + bflo(v4.z) + bflo(v5.z) + bflo(v6.z) + bflo(v7.z);
            a1.y += bfhi(v0.z) + bfhi(v1.z) + bfhi(v2.z) + bfhi(v3.z)
                  + bfhi(v4.z) + bfhi(v5.z) + bfhi(v6.z) + bfhi(v7.z);
            a1.z += bflo(v0.w) + bflo(v1.w) + bflo(v2.w) + bflo(v3.w)
                  + bflo(v4.w) + bflo(v5.w) + bflo(v6.w) + bflo(v7.w);
            a1.w += bfhi(v0.w) + bfhi(v1.w) + bfhi(v2.w) + bfhi(v3.w)
                  + bfhi(v4.w) + bfhi(v5.w) + bfhi(v6.w) + bfhi(v7.w);
        }
        for (; j < end; ++j) {
            int s = csr_src[j];
            uint4 v = ((const uint4*)(tb + (size_t)s * PF))[l2];
            a0.x += bflo(v.x); a0.y += bfhi(v.x); a0.z += bflo(v.y); a0.w += bfhi(v.y);
            a1.x += bflo(v.z); a1.y += bfhi(v.z); a1.z += bflo(v.w); a1.w += bfhi(v.w);
        }
        float dv = dinv[node];
        r0.x = a0.x * dv; r0.y = a0.y * dv; r0.z = a0.z * dv; r0.w = a0.w * dv;
        r1.x = a1.x * dv; r1.y = a1.y * dv; r1.z = a1.z * dv; r1.w = a1.w * dv;
        float4* ar = (float4*)(agg + (size_t)node * HID + plane * PF + l2 * 8);
        ar[0] = r0;
        ar[1] = r1;
    }

    // BN stats for this plane's 16 features (lane holds 8)
    float4 q0, q1;
    q0.x = r0.x * r0.x; q0.y = r0.y * r0.y; q0.z = r0.z * r0.z; q0.w = r0.w * r0.w;
    q1.x = r1.x * r1.x; q1.y = r1.y * r1.y; q1.z = r1.z * r1.z; q1.w = r1.w * r1.w;
#pragma unroll
    for (int off = 2; off < 64; off <<= 1) {
        r0.x += __shfl_xor(r0.x, off, 64); q0.x += __shfl_xor(q0.x, off, 64);
        r0.y += __shfl_xor(r0.y, off, 64); q0.y += __shfl_xor(q0.y, off, 64);
        r0.z += __shfl_xor(r0.z, off, 64); q0.z += __shfl_xor(q0.z, off, 64);
        r0.w += __shfl_xor(r0.w, off, 64); q0.w += __shfl_xor(q0.w, off, 64);
        r1.x += __shfl_xor(r1.x, off, 64); q1.x += __shfl_xor(q1.x, off, 64);
        r1.y += __shfl_xor(r1.y, off, 64); q1.y += __shfl_xor(q1.y, off, 64);
        r1.z += __shfl_xor(r1.z, off, 64); q1.z += __shfl_xor(q1.z, off, 64);
        r1.w += __shfl_xor(r1.w, off, 64); q1.w += __shfl_xor(q1.w, off, 64);
    }
    if ((threadIdx.x & 63) < 2) {
        int f0 = l2 * 8;
        atomicAdd(&lsum[f0 + 0], r0.x); atomicAdd(&lsq[f0 + 0], q0.x);
        atomicAdd(&lsum[f0 + 1], r0.y); atomicAdd(&lsq[f0 + 1], q0.y);
        atomicAdd(&lsum[f0 + 2], r0.z); atomicAdd(&lsq[f0 + 2], q0.z);
        atomicAdd(&lsum[f0 + 3], r0.w); atomicAdd(&lsq[f0 + 3], q0.w);
        atomicAdd(&lsum[f0 + 4], r1.x); atomicAdd(&lsq[f0 + 4], q1.x);
        atomicAdd(&lsum[f0 + 5], r1.y); atomicAdd(&lsq[f0 + 5], q1.y);
        atomicAdd(&lsum[f0 + 6], r1.z); atomicAdd(&lsq[f0 + 6], q1.z);
        atomicAdd(&lsum[f0 + 7], r1.w); atomicAdd(&lsq[f0 + 7], q1.w);
    }
    __syncthreads();
    if (threadIdx.x < PF) {
        atomicAdd(&stats[plane * PF + threadIdx.x], lsum[threadIdx.x]);
        atomicAdd(&stats[HID + plane * PF + threadIdx.x], lsq[threadIdx.x]);
    }
}

// final: h = relu(bn(agg)) + h
__global__ __launch_bounds__(256) void k_bn_apply(const float* __restrict__ agg,
                                                  const float* __restrict__ stats,
                                                  const float* __restrict__ gamma,
                                                  const float* __restrict__ beta,
                                                  float* __restrict__ h, int n, float invN) {
    int gid = blockIdx.x * blockDim.x + threadIdx.x;
    int node = gid >> 6, f = gid & 63;
    if (node >= n) return;
    float mu = stats[f] * invN;
    float var = fmaxf(stats[HID + f] * invN - mu * mu, 0.0f);
    float bn = (agg[gid] - mu) * rsqrtf(var + BN_EPS) * gamma[f] + beta[f];
    h[gid] = fmaxf(bn, 0.0f) + h[gid];
}

extern "C" void kernel_launch(void* const* d_in, const int* in_sizes, int n_in,
                              void* d_out, int out_size, void* d_ws, size_t ws_size,
                              hipStream_t stream) {
    const float* x       = (const float*)d_in[0];
    const int*   ei      = (const int*)d_in[1];
    const float* W_embed = (const float*)d_in[2];
    const float* b_embed = (const float*)d_in[3];
    const float* W_convs = (const float*)d_in[4];
    const float* b_convs = (const float*)d_in[5];
    const float* gamma   = (const float*)d_in[6];
    const float* beta    = (const float*)d_in[7];
    float* h = (float*)d_out;

    const int n = in_sizes[0] / IN_F;   // 50000
    const int e = in_sizes[1] / 2;      // 800000
    const int* src = ei;
    const int* dst = ei + e;

    unsigned short* t2b = (unsigned short*)d_ws;            // 4 planes * n*16 bf16
    float* agg      = (float*)(t2b + (size_t)n * HID);      // n*HID f32
    float* dinv     = agg + (size_t)n * HID;                // n
    float* statsAll = dinv + n;                             // 3*128
    int*   rowbeg   = (int*)(statsAll + 2 * HID * N_LAYERS);// n
    int*   cnt      = rowbeg + n;                           // n
    int*   cursor   = cnt + n;                              // 1
    unsigned short* csr_src = (unsigned short*)(cursor + 1);// e
    unsigned short* rank    = csr_src + e;                  // e

    const int nodeBlocks  = (n + 255) / 256;
    const int nfBlocks    = (n * HID + 255) / 256;
    const int edgeBlocks  = (e + 255) / 256;
    const int aggBlocks   = ((n + 127) / 128) * NPLANE;  // plane = bid&3 (XCD affinity)
    const int denseBlocks = 1024;

    k_zero<<<nodeBlocks, 256, 0, stream>>>(cnt, cursor, statsAll, n);
    k_hist_rank<<<edgeBlocks, 256, 0, stream>>>(dst, cnt, rank, e);
    k_assign<<<nodeBlocks, 256, 0, stream>>>(cnt, rowbeg, dinv, cursor, n);
    k_fill<<<edgeBlocks, 256, 0, stream>>>(src, dst, rowbeg, rank, csr_src, e);

    const float invN = 1.0f / (float)n;

    k_embed_conv<<<denseBlocks, 256, 0, stream>>>(x, W_embed, b_embed, W_convs, b_convs,
                                                  dinv, h, t2b, n);

    for (int l = 0; l < N_LAYERS; ++l) {
        float* stats = statsAll + (size_t)l * 2 * HID;
        k_aggregate<<<aggBlocks, 256, 0, stream>>>(rowbeg, cnt, csr_src, t2b, dinv,
                                                   agg, stats, n);
        if (l < N_LAYERS - 1) {
            const float* Wl = W_convs + (size_t)(l + 1) * HID * HID;
            const float* bl = b_convs + (size_t)(l + 1) * HID;
            k_bn_conv<<<denseBlocks, 256, 0, stream>>>(agg, stats, gamma, beta, Wl, bl, dinv,
                                                       h, t2b, n, invN);
        } else {
            k_bn_apply<<<nfBlocks, 256, 0, stream>>>(agg, stats, gamma, beta, h, n, invN);
        }
    }
}